// Round 8
// baseline (517.369 us; speedup 1.0000x reference)
//
#include <hip/hip_runtime.h>
#include <stdint.h>

// SNN forward, fused: conv1+scan -> pool1 -> conv2+scan -> pool2 ->
// conv3 -> scan -> fc -> scan. Neuron: u=.75u+x; v=.96875v+u; s=(v>=100); v*=(1-s).
// Spikes as uint8 in d_ws; spike regs packed 4/u32.

#define T 128
#define AI 0.75f
#define AV 0.96875f
#define THETA 100.0f

__device__ __forceinline__ void neuron_step(float x, float& u, float& v, float& s) {
    u = AI * u + x;
    v = AV * v + u;
    s = (v >= THETA) ? 1.0f : 0.0f;
    v = v * (1.0f - s);
}

// ---------------- conv1 + scan fused ----------------------------------------
// in: [16][2][40][40][128] f32 (no delay on input), w: [8][2][3][3] (x20).
// Block: 32 pos x 8 o = 256 rows; 16 chunks of 8 t. conv thread=(pos,t),
// scan thread=row. LDS tile row stride 12 words (b128-aligned, 2-way free).
__global__ __launch_bounds__(256) void conv_scan1(
    const float* __restrict__ in, const float* __restrict__ cw,
    uint8_t* __restrict__ out)
{
    __shared__ float lds[256 * 12];
    int bid = blockIdx.x;                  // 800
    int pc = bid % 50;                     // pos-chunk (uniform)
    int n  = bid / 50;                     // uniform
    int tid = threadIdx.x;
    int t   = tid & 7;
    int pos = tid >> 3;                    // 0..31
    int p   = pc * 32 + pos;               // 0..1599
    int hy = p / 40, wx = p % 40;

    bool okh[3] = {hy > 0, true, hy < 39};
    bool okw[3] = {wx > 0, true, wx < 39};

    float u = 0.f, v = 0.f;
    uint32_t ob[32];

    #pragma unroll
    for (int tb = 0; tb < 16; tb++) {
        int tg = tb * 8 + t;
        // conv phase: 18 taps, 8 outputs
        float tap[18];
        #pragma unroll
        for (int c = 0; c < 2; c++)
            #pragma unroll
            for (int dh = 0; dh < 3; dh++)
                #pragma unroll
                for (int dw = 0; dw < 3; dw++) {
                    bool ok = okh[dh] && okw[dw];
                    tap[c * 9 + dh * 3 + dw] = ok ?
                        in[(((n * 2 + c) * 40 + hy + dh - 1) * 40 + wx + dw - 1) * T + tg] : 0.f;
                }
        __syncthreads();                   // prev scan reads done
        #pragma unroll 1
        for (int o = 0; o < 8; o++) {
            const float* wp = cw + o * 18; // uniform -> s_load
            float a = 0.f;
            #pragma unroll
            for (int q = 0; q < 18; q++) a += wp[q] * tap[q];
            lds[(o * 32 + pos) * 12 + t] = a * 20.0f;
        }
        __syncthreads();
        // scan phase: thread = row
        float4 xa = *(const float4*)&lds[tid * 12];
        float4 xb = *(const float4*)&lds[tid * 12 + 4];
        float s0, s1, s2, s3;
        neuron_step(xa.x, u, v, s0); neuron_step(xa.y, u, v, s1);
        neuron_step(xa.z, u, v, s2); neuron_step(xa.w, u, v, s3);
        ob[tb * 2] = (uint32_t)s0 | ((uint32_t)s1 << 8) |
                     ((uint32_t)s2 << 16) | ((uint32_t)s3 << 24);
        neuron_step(xb.x, u, v, s0); neuron_step(xb.y, u, v, s1);
        neuron_step(xb.z, u, v, s2); neuron_step(xb.w, u, v, s3);
        ob[tb * 2 + 1] = (uint32_t)s0 | ((uint32_t)s1 << 8) |
                         ((uint32_t)s2 << 16) | ((uint32_t)s3 << 24);
    }

    int o = tid >> 5, posr = tid & 31;
    uint32_t* op = (uint32_t*)(out + ((size_t)(n * 8 + o) * 1600 + pc * 32 + posr) * T);
    #pragma unroll
    for (int k = 0; k < 8; k++)
        *(uint4*)&op[k * 4] = make_uint4(ob[k*4], ob[k*4+1], ob[k*4+2], ob[k*4+3]);
}

// ---------------- pool fused: 2x2 sum (u8 adds, no carry) + scan + delay ----
template<int C, int HO, int WO>
__global__ __launch_bounds__(256) void pool_fused(
    const uint8_t* __restrict__ in, const float* __restrict__ pw_ptr,
    uint8_t* __restrict__ out)
{
    __shared__ uint32_t lds[256 * 20];
    int tid = threadIdx.x;
    size_t r0 = (size_t)blockIdx.x * 256;
    float pw = pw_ptr[0];

    float u = 0.f, v = 0.f;
    uint32_t ob[32];
    uint32_t carry = 0;

    #pragma unroll
    for (int tb = 0; tb < 2; tb++) {
        __syncthreads();
        #pragma unroll
        for (int k = 0; k < 4; k++) {
            int f = tid + k * 256;
            int row = f >> 2, q = f & 3;
            int orow = (int)r0 + row;
            int wx = orow % WO;
            int hy = (orow / WO) % HO;
            int c  = (orow / (WO * HO)) % C;
            int nn = orow / (WO * HO * C);
            const uint8_t* p00 = in +
                (((size_t)(nn * C + c) * (2 * HO) + 2 * hy) * (2 * WO) + 2 * wx) * T;
            int off = tb * 64 + q * 16;
            uint4 a = *(const uint4*)(p00 + off);
            uint4 b = *(const uint4*)(p00 + T + off);
            uint4 cc = *(const uint4*)(p00 + 2 * WO * T + off);
            uint4 d = *(const uint4*)(p00 + 2 * WO * T + T + off);
            // per-byte sums <=4: u32 adds never carry across bytes
            *(uint4*)&lds[row * 20 + q * 4] =
                make_uint4(a.x + b.x + cc.x + d.x, a.y + b.y + cc.y + d.y,
                           a.z + b.z + cc.z + d.z, a.w + b.w + cc.w + d.w);
        }
        __syncthreads();
        #pragma unroll
        for (int q = 0; q < 4; q++) {
            uint4 w = *(const uint4*)&lds[tid * 20 + q * 4];
            uint32_t words[4] = {w.x, w.y, w.z, w.w};
            #pragma unroll
            for (int j = 0; j < 4; j++) {
                uint32_t cur = words[j];
                uint32_t del = (cur << 8) | carry;   // delay_shift bytes
                carry = cur >> 24;
                float s0, s1, s2, s3;
                neuron_step(pw * (float)(del & 0xffu),         u, v, s0);
                neuron_step(pw * (float)((del >> 8) & 0xffu),  u, v, s1);
                neuron_step(pw * (float)((del >> 16) & 0xffu), u, v, s2);
                neuron_step(pw * (float)((del >> 24) & 0xffu), u, v, s3);
                ob[tb * 16 + q * 4 + j] = (uint32_t)s0 | ((uint32_t)s1 << 8) |
                                          ((uint32_t)s2 << 16) | ((uint32_t)s3 << 24);
            }
        }
    }

    uint32_t* op = (uint32_t*)(out + (r0 + tid) * T);
    #pragma unroll
    for (int k = 0; k < 8; k++)
        *(uint4*)&op[k * 4] = make_uint4(ob[k*4], ob[k*4+1], ob[k*4+2], ob[k*4+3]);
}

// ---------------- conv2 + scan fused ----------------------------------------
// in s2: [16][8][20][20][128] u8 (delayed read), w: [16][8][3][3] (x100).
// Block: 16 pos x 16 o = 256 rows; 8 chunks of 16 t. conv thread=(pos,t) does
// all 16 o (taps loaded once); scan thread=row.
__global__ __launch_bounds__(256) void conv_scan2(
    const uint8_t* __restrict__ in, const float* __restrict__ cw,
    uint8_t* __restrict__ out)
{
    __shared__ float lds[256 * 20];
    int bid = blockIdx.x;                  // 400
    int pc = bid % 25;                     // uniform
    int n  = bid / 25;                     // uniform
    int tid = threadIdx.x;
    int t   = tid & 15;
    int pos = tid >> 4;                    // 0..15
    int p   = pc * 16 + pos;               // 0..399
    int hy = p / 20, wx = p % 20;

    bool okh[3] = {hy > 0, true, hy < 19};
    bool okw[3] = {wx > 0, true, wx < 19};
    const uint8_t* base = in + ((size_t)(n * 8) * 400 + hy * 20 + wx) * T;

    float u = 0.f, v = 0.f;
    uint32_t ob[32];

    #pragma unroll
    for (int tb = 0; tb < 8; tb++) {
        int tg = tb * 16 + t;
        int tm = (tg == 0) ? 0 : (tg - 1);          // delay_shift
        float sm = (tg == 0) ? 0.0f : 100.0f;       // scale * tmask

        float acc[16];
        #pragma unroll
        for (int oi = 0; oi < 16; oi++) acc[oi] = 0.f;

        #pragma unroll 1
        for (int c = 0; c < 8; c++) {
            float tap[9];
            #pragma unroll
            for (int dh = 0; dh < 3; dh++)
                #pragma unroll
                for (int dw = 0; dw < 3; dw++) {
                    bool ok = okh[dh] && okw[dw];
                    tap[dh * 3 + dw] = ok ?
                        (float)base[((size_t)c * 400 + (dh - 1) * 20 + (dw - 1)) * T + tm] : 0.f;
                }
            #pragma unroll
            for (int oi = 0; oi < 16; oi++) {
                if ((oi & 3) == 0) __builtin_amdgcn_sched_barrier(0);
                const float* wp = cw + (oi * 8 + c) * 9;   // uniform
                float a = acc[oi];
                #pragma unroll
                for (int q = 0; q < 9; q++) a += wp[q] * tap[q];
                acc[oi] = a;
            }
        }
        __syncthreads();                   // prev scan reads done
        #pragma unroll
        for (int oi = 0; oi < 16; oi++)
            lds[(oi * 16 + pos) * 20 + t] = acc[oi] * sm;
        __syncthreads();
        // scan: thread = row
        #pragma unroll
        for (int k = 0; k < 4; k++) {
            float4 xv = *(const float4*)&lds[tid * 20 + k * 4];
            float s0, s1, s2, s3;
            neuron_step(xv.x, u, v, s0); neuron_step(xv.y, u, v, s1);
            neuron_step(xv.z, u, v, s2); neuron_step(xv.w, u, v, s3);
            ob[tb * 4 + k] = (uint32_t)s0 | ((uint32_t)s1 << 8) |
                             ((uint32_t)s2 << 16) | ((uint32_t)s3 << 24);
        }
    }

    int o = tid >> 4, posr = tid & 15;
    uint32_t* op = (uint32_t*)(out + ((size_t)(n * 16 + o) * 400 + pc * 16 + posr) * T);
    #pragma unroll
    for (int k = 0; k < 8; k++)
        *(uint4*)&op[k * 4] = make_uint4(ob[k*4], ob[k*4+1], ob[k*4+2], ob[k*4+3]);
}

// ---------------- conv3 phase A (unchanged two-phase; occupancy) ------------
template<int CIN, int COUT_PER, int G, int H, int W>
__global__ __launch_bounds__(256) void conv_x_all(
    const uint8_t* __restrict__ in, const float* __restrict__ cw, float scale,
    float* __restrict__ xout)
{
    constexpr int BPG = H * W * T / 256;
    int bid = blockIdx.x;
    int tIdx = (bid % BPG) * 256 + threadIdx.x;
    int gn = bid / BPG;
    int g = gn % G;                             // uniform
    int n = gn / G;                             // uniform
    int t  = tIdx % T;
    int wx = (tIdx / T) % W;
    int hy = tIdx / (T * W);

    int tm = (t == 0) ? 0 : (t - 1);
    float tmask = (t == 0) ? 0.0f : 1.0f;

    bool okh[3] = {hy > 0, true, hy < H - 1};
    bool okw[3] = {wx > 0, true, wx < W - 1};

    const uint8_t* base = in + ((n * CIN * H + hy) * W + wx) * T + tm;
    const float* wbase = cw + g * COUT_PER * CIN * 9;

    float acc[COUT_PER];
    #pragma unroll
    for (int oi = 0; oi < COUT_PER; oi++) acc[oi] = 0.f;

    #pragma unroll 1
    for (int c = 0; c < CIN; c++) {
        float tap[9];
        #pragma unroll
        for (int dh = 0; dh < 3; dh++)
            #pragma unroll
            for (int dw = 0; dw < 3; dw++) {
                bool ok = okh[dh] && okw[dw];
                tap[dh * 3 + dw] = ok ?
                    (float)base[(c * H * W + (dh - 1) * W + (dw - 1)) * T] : 0.f;
            }
        #pragma unroll
        for (int oi = 0; oi < COUT_PER; oi++) {
            if ((oi & 3) == 0) __builtin_amdgcn_sched_barrier(0);
            const float* wp = wbase + (oi * CIN + c) * 9;
            float a = acc[oi];
            #pragma unroll
            for (int q = 0; q < 9; q++) a += wp[q] * tap[q];
            acc[oi] = a;
        }
    }

    float sm = scale * tmask;
    #pragma unroll
    for (int oi = 0; oi < COUT_PER; oi++) {
        int o = g * COUT_PER + oi;
        xout[((n * (G * COUT_PER) + o) * H * W + hy * W + wx) * T + t] = acc[oi] * sm;
    }
}

// ---------------- scan (transposed via LDS): fp32 x rows -> u8 spikes -------
__global__ __launch_bounds__(256) void scan_spike_t(
    const float* __restrict__ x, uint8_t* __restrict__ out)
{
    __shared__ float lds[256 * 20];
    int tid = threadIdx.x;
    size_t r0 = (size_t)blockIdx.x * 256;
    const float* xb = x + r0 * T;

    float u = 0.f, v = 0.f;
    uint32_t ob[32];

    #pragma unroll
    for (int tb = 0; tb < 8; tb++) {
        __syncthreads();
        #pragma unroll
        for (int k = 0; k < 4; k++) {
            int f = tid + k * 256;
            int row = f >> 2, q = f & 3;
            float4 vv = *(const float4*)(xb + (size_t)row * T + tb * 16 + q * 4);
            *(float4*)&lds[row * 20 + q * 4] = vv;
        }
        __syncthreads();
        #pragma unroll
        for (int k = 0; k < 4; k++) {
            float4 xv = *(const float4*)&lds[tid * 20 + k * 4];
            float s0, s1, s2, s3;
            neuron_step(xv.x, u, v, s0); neuron_step(xv.y, u, v, s1);
            neuron_step(xv.z, u, v, s2); neuron_step(xv.w, u, v, s3);
            ob[tb * 4 + k] = (uint32_t)s0 | ((uint32_t)s1 << 8) |
                             ((uint32_t)s2 << 16) | ((uint32_t)s3 << 24);
        }
    }

    uint32_t* op = (uint32_t*)(out + (r0 + tid) * T);
    #pragma unroll
    for (int k = 0; k < 8; k++)
        *(uint4*)&op[k * 4] = make_uint4(ob[k*4], ob[k*4+1], ob[k*4+2], ob[k*4+3]);
}

// ---------------- W transpose: fwT[c][o] = fw[o][c] -------------------------
__global__ __launch_bounds__(256) void transpose_w(
    const float* __restrict__ fw, float* __restrict__ fwT)
{
    __shared__ float tile[32][33];
    int bc = blockIdx.x % 100;
    int bo = blockIdx.x / 100;
    int lx = threadIdx.x & 31;
    int ly = threadIdx.x >> 5;
    #pragma unroll
    for (int k = 0; k < 4; k++)
        tile[ly + 8 * k][lx] = fw[(bo * 32 + ly + 8 * k) * 3200 + bc * 32 + lx];
    __syncthreads();
    #pragma unroll
    for (int k = 0; k < 4; k++)
        fwT[(bc * 32 + ly + 8 * k) * 512 + bo * 32 + lx] = tile[lx][ly + 8 * k];
}

// ---------------- FC GEMM: c-split 16 (grid 1024 = 4 blocks/CU avail) -------
#define FC_CC 40
#define FC_ROW 140
#define FC_CRANGE 200

__global__ __launch_bounds__(256) void fc_gemm(
    const uint8_t* __restrict__ s5,   // [16][3200][128]
    const float* __restrict__ fwT,    // [3200][512]
    float* __restrict__ ypart)        // [16][16][128][512]
{
    __shared__ float ldsW[FC_CC * FC_ROW];
    __shared__ float ldsS[FC_CC * FC_ROW];

    int bid = blockIdx.x;
    int ks = bid & 15;
    int n  = (bid >> 4) & 15;
    int ob = bid >> 8;                // 0..3
    int o0 = ob * 128;
    int cbase = ks * FC_CRANGE;

    int tid = threadIdx.x;
    int og = tid & 15;
    int tg = tid >> 4;
    int wo = og * 8 + ((og >> 2) << 2);
    int so = tg * 8 + ((tg >> 2) << 2);

    int srow = tid >> 5;              // 0..7
    int scol = tid & 31;              // 0..31
    int sw   = scol * 4 + ((scol >> 3) << 2);

    float acc[8][8];
    #pragma unroll
    for (int i = 0; i < 8; i++)
        #pragma unroll
        for (int j = 0; j < 8; j++) acc[i][j] = 0.f;

    float4 wr4[5];
    uint32_t sr4[5];

    {   // preload chunk 0
        #pragma unroll
        for (int p = 0; p < 5; p++) {
            int c = cbase + p * 8 + srow;
            wr4[p] = *(const float4*)(fwT + (size_t)c * 512 + o0 + scol * 4);
            sr4[p] = *(const uint32_t*)(s5 + ((size_t)n * 3200 + c) * T + scol * 4);
        }
    }

    for (int ch = 0; ch < 5; ch++) {
        __syncthreads();
        #pragma unroll
        for (int p = 0; p < 5; p++) {
            int cc = p * 8 + srow;
            *(float4*)&ldsW[cc * FC_ROW + sw] = wr4[p];
            uint32_t raw = sr4[p];
            uint32_t prv = (uint32_t)__shfl_up((int)raw, 1);
            float f0 = (scol == 0) ? 0.f : (float)((prv >> 24) & 0xffu);
            float f1 = (float)(raw & 0xffu);
            float f2 = (float)((raw >> 8) & 0xffu);
            float f3 = (float)((raw >> 16) & 0xffu);
            *(float4*)&ldsS[cc * FC_ROW + sw] = make_float4(f0, f1, f2, f3);
        }
        __syncthreads();
        if (ch < 4) {
            int c0 = cbase + (ch + 1) * FC_CC;
            #pragma unroll
            for (int p = 0; p < 5; p++) {
                int c = c0 + p * 8 + srow;
                wr4[p] = *(const float4*)(fwT + (size_t)c * 512 + o0 + scol * 4);
                sr4[p] = *(const uint32_t*)(s5 + ((size_t)n * 3200 + c) * T + scol * 4);
            }
        }
        #pragma unroll 4
        for (int cc = 0; cc < FC_CC; cc++) {
            const float* wr = &ldsW[cc * FC_ROW];
            const float* sr = &ldsS[cc * FC_ROW];
            float4 w0 = *(const float4*)(wr + wo);
            float4 w1 = *(const float4*)(wr + wo + 4);
            float4 sA = *(const float4*)(sr + so);
            float4 sB = *(const float4*)(sr + so + 4);
            float wv[8] = {w0.x, w0.y, w0.z, w0.w, w1.x, w1.y, w1.z, w1.w};
            float sv[8] = {sA.x, sA.y, sA.z, sA.w, sB.x, sB.y, sB.z, sB.w};
            #pragma unroll
            for (int i = 0; i < 8; i++)
                #pragma unroll
                for (int j = 0; j < 8; j++)
                    acc[i][j] += wv[i] * sv[j];
        }
    }

    float* yp = ypart + ((size_t)(ks * 16 + n) * T) * 512;
    #pragma unroll
    for (int j = 0; j < 8; j++) {
        int t = tg * 8 + j;
        float4 v0 = make_float4(acc[0][j], acc[1][j], acc[2][j], acc[3][j]);
        float4 v1 = make_float4(acc[4][j], acc[5][j], acc[6][j], acc[7][j]);
        *(float4*)&yp[t * 512 + o0 + og * 8]     = v0;
        *(float4*)&yp[t * 512 + o0 + og * 8 + 4] = v1;
    }
}

// ---------------- FC partial reduce (16 partials, float4) -------------------
__global__ __launch_bounds__(256) void fc_reduce(
    const float4* __restrict__ yp, float4* __restrict__ ys)
{
    int id = blockIdx.x * 256 + threadIdx.x;          // 262,144
    float4 x = yp[id];
    #pragma unroll
    for (int k = 1; k < 16; k++) {
        float4 y = yp[(size_t)k * 262144 + id];
        x.x += y.x; x.y += y.y; x.z += y.z; x.w += y.w;
    }
    ys[id] = x;
}

__global__ __launch_bounds__(64) void fc_scan(
    const float* __restrict__ ysum,   // [16][128][512]
    float* __restrict__ out)          // [16][512][128]
{
    int id = blockIdx.x * 64 + threadIdx.x;           // 8192
    int o = id & 511;
    int n = id >> 9;
    float u = 0.f, v = 0.f;
    float prev = 0.f;                 // final delay_shift
    for (int tb = 0; tb < T / 4; tb++) {
        float b0, b1, b2, b3;
        float x, s;
        x = ysum[(n * T + tb * 4 + 0) * 512 + o]; neuron_step(x, u, v, s); b0 = prev; prev = s;
        x = ysum[(n * T + tb * 4 + 1) * 512 + o]; neuron_step(x, u, v, s); b1 = prev; prev = s;
        x = ysum[(n * T + tb * 4 + 2) * 512 + o]; neuron_step(x, u, v, s); b2 = prev; prev = s;
        x = ysum[(n * T + tb * 4 + 3) * 512 + o]; neuron_step(x, u, v, s); b3 = prev; prev = s;
        *(float4*)&out[((size_t)(n * 512 + o)) * T + tb * 4] = make_float4(b0, b1, b2, b3);
    }
}

// ---------------- launch ----------------------------------------------------
extern "C" void kernel_launch(void* const* d_in, const int* in_sizes, int n_in,
                              void* d_out, int out_size, void* d_ws, size_t ws_size,
                              hipStream_t stream) {
    const float* spike = (const float*)d_in[0];   // [16][2][40][40][128]
    const float* c1w   = (const float*)d_in[1];   // [8][2][3][3]
    const float* c2w   = (const float*)d_in[2];   // [16][8][3][3]
    const float* c3w   = (const float*)d_in[3];   // [32][16][3][3]
    const float* p1w   = (const float*)d_in[4];   // scalar
    const float* p2w   = (const float*)d_in[5];   // scalar
    const float* fcw   = (const float*)d_in[6];   // [512][3200]
    float* out = (float*)d_out;                   // [16][512][128]

    char* ws = (char*)d_ws;
    uint8_t* s1 = (uint8_t*)(ws);                 // 26,214,400
    uint8_t* s2 = (uint8_t*)(ws + 26214400);      //  6,553,600
    uint8_t* s3 = (uint8_t*)(ws + 32768000);      // 13,107,200
    uint8_t* s4 = (uint8_t*)(ws + 45875200);      //  3,276,800
    uint8_t* s5 = (uint8_t*)(ws + 49152000);      //  6,553,600 (ends 55,705,600)
    float* xbuf3 = (float*)(ws + 55705600);       // 26,214,400 (conv3 x)
    float* fwT   = (float*)(ws + 81920000);       //  6,553,600
    float* ypart = (float*)(ws + 88473600);       // 67,108,864
    float* ysumb = (float*)(ws + 155582464);      //  4,194,304 (ends 159,776,768)

    conv_scan1<<<800, 256, 0, stream>>>(spike, c1w, s1);
    transpose_w<<<1600, 256, 0, stream>>>(fcw, fwT);
    pool_fused<8, 20, 20><<<200, 256, 0, stream>>>(s1, p1w, s2);
    conv_scan2<<<400, 256, 0, stream>>>(s2, c2w, s3);
    pool_fused<16, 10, 10><<<100, 256, 0, stream>>>(s3, p2w, s4);
    conv_x_all<16, 16, 2, 10, 10><<<1600, 256, 0, stream>>>(s4, c3w, 100.0f, xbuf3);
    scan_spike_t<<<200, 256, 0, stream>>>(xbuf3, s5);
    fc_gemm<<<1024, 256, 0, stream>>>(s5, fwT, ypart);
    fc_reduce<<<1024, 256, 0, stream>>>((const float4*)ypart, (float4*)ysumb);
    fc_scan<<<128, 64, 0, stream>>>(ysumb, out);
}

// Round 9
// 391.224 us; speedup vs baseline: 1.3224x; 1.3224x over previous
//
#include <hip/hip_runtime.h>
#include <stdint.h>

// SNN forward: conv1 -> scan -> pool1(fused) -> conv2 -> scan -> pool2(fused)
// -> conv3 -> scan -> fc -> reduce -> scan.
// Neuron: u=.75u+x; v=.96875v+u; s=(v>=100); v*=(1-s). Spikes u8 in d_ws.
// Fusion lesson (R8): fusing scan into conv shrinks grid 8x and breaks
// t-coalescing -> keep conv (parallel over t) and scan (parallel over rows)
// as separate kernels with a fp32 bounce buffer.

#define T 128
#define AI 0.75f
#define AV 0.96875f
#define THETA 100.0f

__device__ __forceinline__ void neuron_step(float x, float& u, float& v, float& s) {
    u = AI * u + x;
    v = AV * v + u;
    s = (v >= THETA) ? 1.0f : 0.0f;
    v = v * (1.0f - s);
}

// ---------------- conv1 phase A: x[n][o][h][w][t], lanes over t -------------
__global__ __launch_bounds__(256) void conv1_x(
    const float* __restrict__ in, const float* __restrict__ cw,
    float* __restrict__ xout)
{
    int bid = blockIdx.x;                       // 12800
    int tIdx = (bid % 800) * 256 + threadIdx.x; // within [40][40][128]
    int n = bid / 800;
    int t  = tIdx % T;
    int wx = (tIdx / T) % 40;
    int hy = tIdx / (T * 40);

    float val[18];
    #pragma unroll
    for (int c = 0; c < 2; c++)
      #pragma unroll
      for (int dh = -1; dh <= 1; dh++)
        #pragma unroll
        for (int dw = -1; dw <= 1; dw++) {
            int q = c * 9 + (dh + 1) * 3 + (dw + 1);
            int hh = hy + dh, ww = wx + dw;
            bool ok = (hh >= 0) && (hh < 40) && (ww >= 0) && (ww < 40);
            val[q] = ok ? in[(((n * 2 + c) * 40 + hh) * 40 + ww) * T + t] : 0.0f;
        }

    #pragma unroll 1
    for (int o = 0; o < 8; o++) {
        const float* wp = cw + o * 18;          // uniform -> s_load
        float a = 0.f;
        #pragma unroll
        for (int q = 0; q < 18; q++) a += wp[q] * val[q];
        xout[(((n * 8 + o) * 40 + hy) * 40 + wx) * T + t] = a * 20.0f;
    }
}

// ---------------- scan (transposed via LDS): fp32 x rows -> u8 spikes -------
__global__ __launch_bounds__(256) void scan_spike_t(
    const float* __restrict__ x, uint8_t* __restrict__ out)
{
    __shared__ float lds[256 * 20];
    int tid = threadIdx.x;
    size_t r0 = (size_t)blockIdx.x * 256;
    const float* xb = x + r0 * T;

    float u = 0.f, v = 0.f;
    uint32_t ob[32];

    #pragma unroll
    for (int tb = 0; tb < 8; tb++) {
        __syncthreads();
        #pragma unroll
        for (int k = 0; k < 4; k++) {
            int f = tid + k * 256;
            int row = f >> 2, q = f & 3;
            float4 vv = *(const float4*)(xb + (size_t)row * T + tb * 16 + q * 4);
            *(float4*)&lds[row * 20 + q * 4] = vv;
        }
        __syncthreads();
        #pragma unroll
        for (int k = 0; k < 4; k++) {
            float4 xv = *(const float4*)&lds[tid * 20 + k * 4];
            float s0, s1, s2, s3;
            neuron_step(xv.x, u, v, s0); neuron_step(xv.y, u, v, s1);
            neuron_step(xv.z, u, v, s2); neuron_step(xv.w, u, v, s3);
            ob[tb * 4 + k] = (uint32_t)s0 | ((uint32_t)s1 << 8) |
                             ((uint32_t)s2 << 16) | ((uint32_t)s3 << 24);
        }
    }

    uint32_t* op = (uint32_t*)(out + (r0 + tid) * T);
    #pragma unroll
    for (int k = 0; k < 8; k++)
        *(uint4*)&op[k * 4] = make_uint4(ob[k*4], ob[k*4+1], ob[k*4+2], ob[k*4+3]);
}

// ---------------- pool fused: 2x2 sum (u8 adds, no carry) + scan + delay ----
template<int C, int HO, int WO>
__global__ __launch_bounds__(256) void pool_fused(
    const uint8_t* __restrict__ in, const float* __restrict__ pw_ptr,
    uint8_t* __restrict__ out)
{
    __shared__ uint32_t lds[256 * 20];
    int tid = threadIdx.x;
    size_t r0 = (size_t)blockIdx.x * 256;
    float pw = pw_ptr[0];

    float u = 0.f, v = 0.f;
    uint32_t ob[32];
    uint32_t carry = 0;

    #pragma unroll
    for (int tb = 0; tb < 2; tb++) {
        __syncthreads();
        #pragma unroll
        for (int k = 0; k < 4; k++) {
            int f = tid + k * 256;
            int row = f >> 2, q = f & 3;
            int orow = (int)r0 + row;
            int wx = orow % WO;
            int hy = (orow / WO) % HO;
            int c  = (orow / (WO * HO)) % C;
            int nn = orow / (WO * HO * C);
            const uint8_t* p00 = in +
                (((size_t)(nn * C + c) * (2 * HO) + 2 * hy) * (2 * WO) + 2 * wx) * T;
            int off = tb * 64 + q * 16;
            uint4 a = *(const uint4*)(p00 + off);
            uint4 b = *(const uint4*)(p00 + T + off);
            uint4 cc = *(const uint4*)(p00 + 2 * WO * T + off);
            uint4 d = *(const uint4*)(p00 + 2 * WO * T + T + off);
            *(uint4*)&lds[row * 20 + q * 4] =
                make_uint4(a.x + b.x + cc.x + d.x, a.y + b.y + cc.y + d.y,
                           a.z + b.z + cc.z + d.z, a.w + b.w + cc.w + d.w);
        }
        __syncthreads();
        #pragma unroll
        for (int q = 0; q < 4; q++) {
            uint4 w = *(const uint4*)&lds[tid * 20 + q * 4];
            uint32_t words[4] = {w.x, w.y, w.z, w.w};
            #pragma unroll
            for (int j = 0; j < 4; j++) {
                uint32_t cur = words[j];
                uint32_t del = (cur << 8) | carry;   // delay_shift bytes
                carry = cur >> 24;
                float s0, s1, s2, s3;
                neuron_step(pw * (float)(del & 0xffu),         u, v, s0);
                neuron_step(pw * (float)((del >> 8) & 0xffu),  u, v, s1);
                neuron_step(pw * (float)((del >> 16) & 0xffu), u, v, s2);
                neuron_step(pw * (float)((del >> 24) & 0xffu), u, v, s3);
                ob[tb * 16 + q * 4 + j] = (uint32_t)s0 | ((uint32_t)s1 << 8) |
                                          ((uint32_t)s2 << 16) | ((uint32_t)s3 << 24);
            }
        }
    }

    uint32_t* op = (uint32_t*)(out + (r0 + tid) * T);
    #pragma unroll
    for (int k = 0; k < 8; k++)
        *(uint4*)&op[k * 4] = make_uint4(ob[k*4], ob[k*4+1], ob[k*4+2], ob[k*4+3]);
}

// ---------------- conv phase A (grouped): COUT_PER outputs per thread -------
template<int CIN, int COUT_PER, int G, int H, int W>
__global__ __launch_bounds__(256) void conv_x_all(
    const uint8_t* __restrict__ in, const float* __restrict__ cw, float scale,
    float* __restrict__ xout)
{
    constexpr int BPG = H * W * T / 256;
    int bid = blockIdx.x;
    int tIdx = (bid % BPG) * 256 + threadIdx.x;
    int gn = bid / BPG;
    int g = gn % G;                             // uniform
    int n = gn / G;                             // uniform
    int t  = tIdx % T;
    int wx = (tIdx / T) % W;
    int hy = tIdx / (T * W);

    int tm = (t == 0) ? 0 : (t - 1);
    float tmask = (t == 0) ? 0.0f : 1.0f;

    bool okh[3] = {hy > 0, true, hy < H - 1};
    bool okw[3] = {wx > 0, true, wx < W - 1};

    const uint8_t* base = in + ((n * CIN * H + hy) * W + wx) * T + tm;
    const float* wbase = cw + g * COUT_PER * CIN * 9;

    float acc[COUT_PER];
    #pragma unroll
    for (int oi = 0; oi < COUT_PER; oi++) acc[oi] = 0.f;

    #pragma unroll 1
    for (int c = 0; c < CIN; c++) {
        float tap[9];
        #pragma unroll
        for (int dh = 0; dh < 3; dh++)
            #pragma unroll
            for (int dw = 0; dw < 3; dw++) {
                bool ok = okh[dh] && okw[dw];
                tap[dh * 3 + dw] = ok ?
                    (float)base[(c * H * W + (dh - 1) * W + (dw - 1)) * T] : 0.f;
            }
        #pragma unroll
        for (int oi = 0; oi < COUT_PER; oi++) {
            if ((oi & 3) == 0) __builtin_amdgcn_sched_barrier(0);
            const float* wp = wbase + (oi * CIN + c) * 9;
            float a = acc[oi];
            #pragma unroll
            for (int q = 0; q < 9; q++) a += wp[q] * tap[q];
            acc[oi] = a;
        }
    }

    float sm = scale * tmask;
    #pragma unroll
    for (int oi = 0; oi < COUT_PER; oi++) {
        int o = g * COUT_PER + oi;
        xout[((n * (G * COUT_PER) + o) * H * W + hy * W + wx) * T + t] = acc[oi] * sm;
    }
}

// ---------------- W transpose: fwT[c][o] = fw[o][c] -------------------------
__global__ __launch_bounds__(256) void transpose_w(
    const float* __restrict__ fw, float* __restrict__ fwT)
{
    __shared__ float tile[32][33];
    int bc = blockIdx.x % 100;
    int bo = blockIdx.x / 100;
    int lx = threadIdx.x & 31;
    int ly = threadIdx.x >> 5;
    #pragma unroll
    for (int k = 0; k < 4; k++)
        tile[ly + 8 * k][lx] = fw[(bo * 32 + ly + 8 * k) * 3200 + bc * 32 + lx];
    __syncthreads();
    #pragma unroll
    for (int k = 0; k < 4; k++)
        fwT[(bc * 32 + ly + 8 * k) * 512 + bo * 32 + lx] = tile[lx][ly + 8 * k];
}

// ---------------- FC GEMM: c-split 16 (grid 1024 = 4 blocks/CU) -------------
#define FC_CC 40
#define FC_ROW 140
#define FC_CRANGE 200

__global__ __launch_bounds__(256) void fc_gemm(
    const uint8_t* __restrict__ s5,   // [16][3200][128]
    const float* __restrict__ fwT,    // [3200][512]
    float* __restrict__ ypart)        // [16][16][128][512]
{
    __shared__ float ldsW[FC_CC * FC_ROW];
    __shared__ float ldsS[FC_CC * FC_ROW];

    int bid = blockIdx.x;
    int ks = bid & 15;
    int n  = (bid >> 4) & 15;
    int ob = bid >> 8;                // 0..3
    int o0 = ob * 128;
    int cbase = ks * FC_CRANGE;

    int tid = threadIdx.x;
    int og = tid & 15;
    int tg = tid >> 4;
    int wo = og * 8 + ((og >> 2) << 2);
    int so = tg * 8 + ((tg >> 2) << 2);

    int srow = tid >> 5;              // 0..7
    int scol = tid & 31;              // 0..31
    int sw   = scol * 4 + ((scol >> 3) << 2);

    float acc[8][8];
    #pragma unroll
    for (int i = 0; i < 8; i++)
        #pragma unroll
        for (int j = 0; j < 8; j++) acc[i][j] = 0.f;

    float4 wr4[5];
    uint32_t sr4[5];

    {   // preload chunk 0
        #pragma unroll
        for (int p = 0; p < 5; p++) {
            int c = cbase + p * 8 + srow;
            wr4[p] = *(const float4*)(fwT + (size_t)c * 512 + o0 + scol * 4);
            sr4[p] = *(const uint32_t*)(s5 + ((size_t)n * 3200 + c) * T + scol * 4);
        }
    }

    for (int ch = 0; ch < 5; ch++) {
        __syncthreads();
        #pragma unroll
        for (int p = 0; p < 5; p++) {
            int cc = p * 8 + srow;
            *(float4*)&ldsW[cc * FC_ROW + sw] = wr4[p];
            uint32_t raw = sr4[p];
            uint32_t prv = (uint32_t)__shfl_up((int)raw, 1);
            float f0 = (scol == 0) ? 0.f : (float)((prv >> 24) & 0xffu);
            float f1 = (float)(raw & 0xffu);
            float f2 = (float)((raw >> 8) & 0xffu);
            float f3 = (float)((raw >> 16) & 0xffu);
            *(float4*)&ldsS[cc * FC_ROW + sw] = make_float4(f0, f1, f2, f3);
        }
        __syncthreads();
        if (ch < 4) {
            int c0 = cbase + (ch + 1) * FC_CC;
            #pragma unroll
            for (int p = 0; p < 5; p++) {
                int c = c0 + p * 8 + srow;
                wr4[p] = *(const float4*)(fwT + (size_t)c * 512 + o0 + scol * 4);
                sr4[p] = *(const uint32_t*)(s5 + ((size_t)n * 3200 + c) * T + scol * 4);
            }
        }
        #pragma unroll 4
        for (int cc = 0; cc < FC_CC; cc++) {
            const float* wr = &ldsW[cc * FC_ROW];
            const float* sr = &ldsS[cc * FC_ROW];
            float4 w0 = *(const float4*)(wr + wo);
            float4 w1 = *(const float4*)(wr + wo + 4);
            float4 sA = *(const float4*)(sr + so);
            float4 sB = *(const float4*)(sr + so + 4);
            float wv[8] = {w0.x, w0.y, w0.z, w0.w, w1.x, w1.y, w1.z, w1.w};
            float sv[8] = {sA.x, sA.y, sA.z, sA.w, sB.x, sB.y, sB.z, sB.w};
            #pragma unroll
            for (int i = 0; i < 8; i++)
                #pragma unroll
                for (int j = 0; j < 8; j++)
                    acc[i][j] += wv[i] * sv[j];
        }
    }

    float* yp = ypart + ((size_t)(ks * 16 + n) * T) * 512;
    #pragma unroll
    for (int j = 0; j < 8; j++) {
        int t = tg * 8 + j;
        float4 v0 = make_float4(acc[0][j], acc[1][j], acc[2][j], acc[3][j]);
        float4 v1 = make_float4(acc[4][j], acc[5][j], acc[6][j], acc[7][j]);
        *(float4*)&yp[t * 512 + o0 + og * 8]     = v0;
        *(float4*)&yp[t * 512 + o0 + og * 8 + 4] = v1;
    }
}

// ---------------- FC partial reduce (16 partials, float4) -------------------
__global__ __launch_bounds__(256) void fc_reduce(
    const float4* __restrict__ yp, float4* __restrict__ ys)
{
    int id = blockIdx.x * 256 + threadIdx.x;          // 262,144
    float4 x = yp[id];
    #pragma unroll
    for (int k = 1; k < 16; k++) {
        float4 y = yp[(size_t)k * 262144 + id];
        x.x += y.x; x.y += y.y; x.z += y.z; x.w += y.w;
    }
    ys[id] = x;
}

__global__ __launch_bounds__(64) void fc_scan(
    const float* __restrict__ ysum,   // [16][128][512]
    float* __restrict__ out)          // [16][512][128]
{
    int id = blockIdx.x * 64 + threadIdx.x;           // 8192
    int o = id & 511;
    int n = id >> 9;
    float u = 0.f, v = 0.f;
    float prev = 0.f;                 // final delay_shift
    for (int tb = 0; tb < T / 4; tb++) {
        float b0, b1, b2, b3;
        float x, s;
        x = ysum[(n * T + tb * 4 + 0) * 512 + o]; neuron_step(x, u, v, s); b0 = prev; prev = s;
        x = ysum[(n * T + tb * 4 + 1) * 512 + o]; neuron_step(x, u, v, s); b1 = prev; prev = s;
        x = ysum[(n * T + tb * 4 + 2) * 512 + o]; neuron_step(x, u, v, s); b2 = prev; prev = s;
        x = ysum[(n * T + tb * 4 + 3) * 512 + o]; neuron_step(x, u, v, s); b3 = prev; prev = s;
        *(float4*)&out[((size_t)(n * 512 + o)) * T + tb * 4] = make_float4(b0, b1, b2, b3);
    }
}

// ---------------- launch ----------------------------------------------------
extern "C" void kernel_launch(void* const* d_in, const int* in_sizes, int n_in,
                              void* d_out, int out_size, void* d_ws, size_t ws_size,
                              hipStream_t stream) {
    const float* spike = (const float*)d_in[0];   // [16][2][40][40][128]
    const float* c1w   = (const float*)d_in[1];   // [8][2][3][3]
    const float* c2w   = (const float*)d_in[2];   // [16][8][3][3]
    const float* c3w   = (const float*)d_in[3];   // [32][16][3][3]
    const float* p1w   = (const float*)d_in[4];   // scalar
    const float* p2w   = (const float*)d_in[5];   // scalar
    const float* fcw   = (const float*)d_in[6];   // [512][3200]
    float* out = (float*)d_out;                   // [16][512][128]

    char* ws = (char*)d_ws;
    // spike buffers
    uint8_t* s1 = (uint8_t*)(ws);                 // 26,214,400
    uint8_t* s2 = (uint8_t*)(ws + 26214400);      //  6,553,600
    uint8_t* s3 = (uint8_t*)(ws + 32768000);      // 13,107,200
    uint8_t* s4 = (uint8_t*)(ws + 45875200);      //  3,276,800
    uint8_t* s5 = (uint8_t*)(ws + 49152000);      //  6,553,600 (ends 55,705,600)
    // region @55,705,600: xbuf1 (conv1 x, 104,857,600) -> xbuf (L2/L3 x,
    // 52,428,800) -> ypart (67,108,864). Sequentially dead, safe aliases.
    float* xbuf1 = (float*)(ws + 55705600);
    float* xbuf  = (float*)(ws + 55705600);
    float* ypart = (float*)(ws + 55705600);
    float* ysumb = (float*)(ws + 122814464);      //  4,194,304 (ends 127,008,768)
    float* fwT   = (float*)(ws + 160563200);      //  6,553,600 (ends 167,116,800)

    conv1_x<<<12800, 256, 0, stream>>>(spike, c1w, xbuf1);
    scan_spike_t<<<800, 256, 0, stream>>>(xbuf1, s1);
    transpose_w<<<1600, 256, 0, stream>>>(fcw, fwT);

    pool_fused<8, 20, 20><<<200, 256, 0, stream>>>(s1, p1w, s2);
    conv_x_all<8, 16, 1, 20, 20><<<3200, 256, 0, stream>>>(s2, c2w, 100.0f, xbuf);
    scan_spike_t<<<400, 256, 0, stream>>>(xbuf, s3);

    pool_fused<16, 10, 10><<<100, 256, 0, stream>>>(s3, p2w, s4);
    conv_x_all<16, 16, 2, 10, 10><<<1600, 256, 0, stream>>>(s4, c3w, 100.0f, xbuf);
    scan_spike_t<<<200, 256, 0, stream>>>(xbuf, s5);

    fc_gemm<<<1024, 256, 0, stream>>>(s5, fwT, ypart);
    fc_reduce<<<1024, 256, 0, stream>>>((const float4*)ypart, (float4*)ysumb);
    fc_scan<<<128, 64, 0, stream>>>(ysumb, out);
}